// Round 3
// baseline (1175.637 us; speedup 1.0000x reference)
//
#include <hip/hip_runtime.h>
#include <hip/hip_bf16.h>

#define NN 50000
#define EE 800000
#define DD 128

typedef __attribute__((ext_vector_type(8))) short bf16x8;
typedef __attribute__((ext_vector_type(4))) float f32x4;

__device__ __forceinline__ short f2bf(float f) {
    __hip_bfloat16 h = __float2bfloat16(f);
    return __builtin_bit_cast(short, h);
}

__device__ __forceinline__ float bf2f(short s) {
    unsigned int u = ((unsigned int)(unsigned short)s) << 16;
    return __builtin_bit_cast(float, u);
}

__device__ __forceinline__ float fast_silu(float x) {
    return x / (1.0f + __expf(-x));
}

// ---- prep: h (fp32) -> bf16, zero hist counters ----
__global__ void prep_kernel(const float* __restrict__ h, unsigned short* __restrict__ hp,
                            int* __restrict__ cnt) {
    int t = blockIdx.x * blockDim.x + threadIdx.x;   // 1.6M threads exactly
    float4 v = ((const float4*)h)[t];
    ushort4 o;
    o.x = (unsigned short)f2bf(v.x);
    o.y = (unsigned short)f2bf(v.y);
    o.z = (unsigned short)f2bf(v.z);
    o.w = (unsigned short)f2bf(v.w);
    ((ushort4*)hp)[t] = o;
    if (t < NN) cnt[t] = 0;
}

// ---- pack 6 weight blocks into MFMA B-frag order + w1c  (+ fused receiver histogram) ----
__global__ void pack_w_kernel(const float* __restrict__ W1, const float* __restrict__ W2,
                              const float* __restrict__ U1, const float* __restrict__ U2,
                              const int* __restrict__ ei,
                              unsigned short* __restrict__ packs,
                              float* __restrict__ w1c_out,
                              int* __restrict__ cnt) {
    int t = blockIdx.x * blockDim.x + threadIdx.x;   // 3510 blocks
    if (t >= 98304) {
        if (t < 98432) { int d = t - 98304; w1c_out[d] = W1[d * 257 + 256]; return; }
        int e = t - 98432;
        if (e < EE) atomicAdd(&cnt[ei[EE + e]], 1);   // histogram of receivers
        return;
    }
    int mat = t >> 14;
    int r = t & 16383;
    int j = r & 7;
    int lane = (r >> 3) & 63;
    int f = r >> 9;            // 0..31
    int ks = f & 3, nt = f >> 2;
    int n = nt * 16 + (lane & 15);
    int k = ks * 32 + (lane >> 4) * 8 + j;
    float v;
    switch (mat) {
        case 0: v = W1[n * 257 + k];        break;  // W1a (vs h_sender)
        case 1: v = W1[n * 257 + 128 + k];  break;  // W1b (vs h_receiver)
        case 2: v = W2[n * 128 + k];        break;  // W2
        case 3: v = U1[n * 256 + k];        break;  // U1a (vs h)
        case 4: v = U1[n * 256 + 128 + k];  break;  // U1b (vs agg)
        default: v = U2[n * 128 + k];       break;  // U2
    }
    packs[t] = (unsigned short)f2bf(v);
}

// ---- counting sort, phase 2: exclusive scan (1 block, 1024 threads) ----
__global__ void scan_kernel(const int* __restrict__ cnt, int* __restrict__ off,
                            int* __restrict__ cursor) {
    __shared__ int part[1024];
    const int t = threadIdx.x;
    const int CH = 49;                               // 1024*49 = 50176 >= NN
    int lo = t * CH, hi = lo + CH;
    if (hi > NN) hi = NN;
    int s = 0;
    for (int i = lo; i < hi; i++) s += cnt[i];
    part[t] = s;
    __syncthreads();
    for (int d = 1; d < 1024; d <<= 1) {
        int v = (t >= d) ? part[t - d] : 0;
        __syncthreads();
        part[t] += v;
        __syncthreads();
    }
    int base = (t == 0) ? 0 : part[t - 1];
    for (int i = lo; i < hi; i++) {
        off[i] = base;
        cursor[i] = base;
        base += cnt[i];
    }
    if (t == 0) off[NN] = EE;
}

// ---- counting sort, phase 3: scatter SENDERS into receiver-sorted order (4B only) ----
__global__ void scatter_kernel(const int* __restrict__ ei, int* __restrict__ cursor,
                               int* __restrict__ csr_send) {
    int e = blockIdx.x * 256 + threadIdx.x;
    int s = ei[e], r = ei[EE + e];
    int pos = atomicAdd(&cursor[r], 1);
    csr_send[pos] = s;
}

// ---- prep_g: per-node G1a = h*W1a^T + b1, G1b = h*W1b^T, stored bf16 [NN][256] ----
__global__ __launch_bounds__(256, 2) void prep_g_kernel(
    const unsigned short* __restrict__ hp,
    const bf16x8* __restrict__ w1a_pack,
    const bf16x8* __restrict__ w1b_pack,
    const float* __restrict__ b1,
    unsigned short* __restrict__ G)
{
    const int tid = threadIdx.x;
    const int wave = tid >> 6, lane = tid & 63;
    const int quad = lane >> 4, l15 = lane & 15;
    const int nbase = blockIdx.x * 64 + wave * 16;

    int n = nbase + l15;
    int nrow = n < NN ? n : NN - 1;

    bf16x8 ah[4];
    #pragma unroll
    for (int ks = 0; ks < 4; ks++)
        ah[ks] = *(const bf16x8*)(hp + (size_t)nrow * DD + ks * 32 + quad * 8);

    f32x4 acca[8], accb[8];
    #pragma unroll
    for (int nt = 0; nt < 8; nt++) {
        acca[nt] = f32x4{0.f, 0.f, 0.f, 0.f};
        accb[nt] = f32x4{0.f, 0.f, 0.f, 0.f};
    }

    #pragma unroll
    for (int ks = 0; ks < 4; ks++) {
        #pragma unroll
        for (int nt = 0; nt < 8; nt++)
            acca[nt] = __builtin_amdgcn_mfma_f32_16x16x32_bf16(
                ah[ks], w1a_pack[(nt * 4 + ks) * 64 + lane], acca[nt], 0, 0, 0);
        #pragma unroll
        for (int nt = 0; nt < 8; nt++)
            accb[nt] = __builtin_amdgcn_mfma_f32_16x16x32_bf16(
                ah[ks], w1b_pack[(nt * 4 + ks) * 64 + lane], accb[nt], 0, 0, 0);
    }

    #pragma unroll
    for (int nt = 0; nt < 8; nt++) {
        int d = nt * 16 + l15;
        float b1v = b1[d];
        #pragma unroll
        for (int r = 0; r < 4; r++) {
            int n2 = nbase + quad * 4 + r;
            if (n2 < NN) {
                G[(size_t)n2 * 256 + d]       = (unsigned short)f2bf(acca[nt][r] + b1v);
                G[(size_t)n2 * 256 + 128 + d] = (unsigned short)f2bf(accb[nt][r]);
            }
        }
    }
}

// ---- fused edge+node kernel: each wave owns 16 consecutive receivers (CSR).
//      Per node: hoist G1b + coords, chunk its edges (16 rows), silu -> W2 MFMA,
//      masked in-register row-sum -> per-wave LDS agg. Then U1/U2 node update
//      from LDS and direct store. ZERO global atomics. ----
__global__ __launch_bounds__(256, 3) void fused_kernel(
    const unsigned short* __restrict__ G,      // [NN][256] bf16: [G1a+b1 | G1b]
    const float* __restrict__ coords,          // [NN][3]
    const int* __restrict__ csr_send,          // [EE] senders, receiver-sorted
    const int* __restrict__ off,               // [NN+1] CSR offsets
    const bf16x8* __restrict__ w2_pack,
    const float* __restrict__ w1c,
    const float* __restrict__ b2,
    const unsigned short* __restrict__ hp,     // [NN][128] bf16 h
    const float* __restrict__ hf,              // [NN][128] fp32 h
    const bf16x8* __restrict__ u1a_pack,
    const bf16x8* __restrict__ u1b_pack,
    const bf16x8* __restrict__ u2_pack,
    const float* __restrict__ c1,
    const float* __restrict__ c2,
    float* __restrict__ out)
{
    __shared__ float agg_s[4][16][132];        // per-wave agg tile (padded)
    __shared__ int offs_s[4][17];

    const int tid = threadIdx.x;
    const int wave = tid >> 6, lane = tid & 63;
    const int quad = lane >> 4, l15 = lane & 15;
    const int nbase = blockIdx.x * 64 + wave * 16;
    if (nbase >= NN) return;                   // NN = 3125*16: inactive waves exit

    if (lane < 17) offs_s[wave][lane] = off[nbase + lane];
    asm volatile("s_waitcnt lgkmcnt(0)" ::: "memory");

    // per-lane constants
    float w1cf[4][8];
    #pragma unroll
    for (int ks = 0; ks < 4; ks++) {
        f32x4 c0 = *(const f32x4*)(w1c + ks * 32 + quad * 8);
        f32x4 cc1 = *(const f32x4*)(w1c + ks * 32 + quad * 8 + 4);
        #pragma unroll
        for (int j = 0; j < 4; j++) { w1cf[ks][j] = c0[j]; w1cf[ks][4 + j] = cc1[j]; }
    }
    float b2f[8];
    #pragma unroll
    for (int nt = 0; nt < 8; nt++) b2f[nt] = b2[nt * 16 + l15];

    // ================= edge phase =================
    for (int n = 0; n < 16; n++) {
        const int eA = __builtin_amdgcn_readfirstlane(offs_s[wave][n]);
        const int eB = __builtin_amdgcn_readfirstlane(offs_s[wave][n + 1]);
        const int rnode = nbase + n;

        // hoist receiver-side data once per node
        bf16x8 gb[4];
        #pragma unroll
        for (int ks = 0; ks < 4; ks++)
            gb[ks] = *(const bf16x8*)(G + (size_t)rnode * 256 + 128 + ks * 32 + quad * 8);
        float cR0 = coords[3 * rnode + 0];
        float cR1 = coords[3 * rnode + 1];
        float cR2 = coords[3 * rnode + 2];

        float sumv[8];
        #pragma unroll
        for (int nt = 0; nt < 8; nt++) sumv[nt] = 0.f;

        for (int ch = eA; ch < eB; ch += 16) {
            // row l15 of this chunk; dummy rows duplicate the last real edge
            int p = ch + l15;
            int sr = csr_send[p < eB ? p : eB - 1];

            bf16x8 ga[4];
            #pragma unroll
            for (int ks = 0; ks < 4; ks++)
                ga[ks] = *(const bf16x8*)(G + (size_t)sr * 256 + ks * 32 + quad * 8);
            float dx = coords[3 * sr + 0] - cR0;
            float dy = coords[3 * sr + 1] - cR1;
            float dz = coords[3 * sr + 2] - cR2;
            float dist = sqrtf(dx * dx + dy * dy + dz * dz);

            // layer-1 epilogue in A-frag layout
            bf16x8 m1f[4];
            #pragma unroll
            for (int ks = 0; ks < 4; ks++) {
                #pragma unroll
                for (int j = 0; j < 8; j++) {
                    float pre = bf2f(ga[ks][j]) + bf2f(gb[ks][j]) + dist * w1cf[ks][j];
                    m1f[ks][j] = f2bf(fast_silu(pre));
                }
            }

            // layer 2: W2 MFMA
            f32x4 acc2[8];
            #pragma unroll
            for (int nt = 0; nt < 8; nt++) acc2[nt] = f32x4{0.f, 0.f, 0.f, 0.f};
            #pragma unroll
            for (int ks = 0; ks < 4; ks++)
                #pragma unroll
                for (int nt = 0; nt < 8; nt++)
                    acc2[nt] = __builtin_amdgcn_mfma_f32_16x16x32_bf16(
                        m1f[ks], w2_pack[(nt * 4 + ks) * 64 + lane], acc2[nt], 0, 0, 0);

            // masked per-edge silu, accumulate rows (C rows = quad*4+r)
            float mk[4];
            #pragma unroll
            for (int r = 0; r < 4; r++)
                mk[r] = (ch + quad * 4 + r < eB) ? 1.f : 0.f;
            #pragma unroll
            for (int nt = 0; nt < 8; nt++)
                #pragma unroll
                for (int r = 0; r < 4; r++)
                    sumv[nt] += mk[r] * fast_silu(acc2[nt][r] + b2f[nt]);
        }

        // cross-quad reduce (rows live in quads: lane bits 4,5) and store row n
        #pragma unroll
        for (int nt = 0; nt < 8; nt++) {
            float v = sumv[nt];
            v += __shfl_xor(v, 16);
            v += __shfl_xor(v, 32);
            if (quad == 0) agg_s[wave][n][nt * 16 + l15] = v;
        }
    }
    asm volatile("s_waitcnt lgkmcnt(0)" ::: "memory");

    // ================= node phase =================
    float c1v[8];
    #pragma unroll
    for (int nt = 0; nt < 8; nt++) c1v[nt] = c1[nt * 16 + l15];

    const int nrow = nbase + l15;              // always < NN for active waves
    bf16x8 ah[4], ag[4];
    #pragma unroll
    for (int ks = 0; ks < 4; ks++) {
        ah[ks] = *(const bf16x8*)(hp + (size_t)nrow * DD + ks * 32 + quad * 8);
        f32x4 g0 = *(const f32x4*)&agg_s[wave][l15][ks * 32 + quad * 8];
        f32x4 g1 = *(const f32x4*)&agg_s[wave][l15][ks * 32 + quad * 8 + 4];
        bf16x8 t;
        t[0] = f2bf(g0[0]); t[1] = f2bf(g0[1]); t[2] = f2bf(g0[2]); t[3] = f2bf(g0[3]);
        t[4] = f2bf(g1[0]); t[5] = f2bf(g1[1]); t[6] = f2bf(g1[2]); t[7] = f2bf(g1[3]);
        ag[ks] = t;
    }

    f32x4 acc[8];
    #pragma unroll
    for (int nt = 0; nt < 8; nt++) acc[nt] = f32x4{0.f, 0.f, 0.f, 0.f};

    #pragma unroll
    for (int ks = 0; ks < 4; ks++) {
        #pragma unroll
        for (int nt = 0; nt < 8; nt++)
            acc[nt] = __builtin_amdgcn_mfma_f32_16x16x32_bf16(
                ah[ks], u1a_pack[(nt * 4 + ks) * 64 + lane], acc[nt], 0, 0, 0);
        #pragma unroll
        for (int nt = 0; nt < 8; nt++)
            acc[nt] = __builtin_amdgcn_mfma_f32_16x16x32_bf16(
                ag[ks], u1b_pack[(nt * 4 + ks) * 64 + lane], acc[nt], 0, 0, 0);
    }

    // stage silu(acc+c1) through (reused) LDS for layer-2 A-frag transpose
    unsigned short* u1s = (unsigned short*)&agg_s[wave][0][0];   // [16][136] ushort
    #pragma unroll
    for (int nt = 0; nt < 8; nt++) {
        int d = nt * 16 + l15;
        #pragma unroll
        for (int r = 0; r < 4; r++) {
            float pre = acc[nt][r] + c1v[nt];
            u1s[(quad * 4 + r) * 136 + d] = (unsigned short)f2bf(fast_silu(pre));
        }
    }
    asm volatile("s_waitcnt lgkmcnt(0)" ::: "memory");

    bf16x8 a2[4];
    #pragma unroll
    for (int ks = 0; ks < 4; ks++)
        a2[ks] = *(const bf16x8*)(u1s + l15 * 136 + ks * 32 + quad * 8);

    f32x4 acc2[8];
    #pragma unroll
    for (int nt = 0; nt < 8; nt++) acc2[nt] = f32x4{0.f, 0.f, 0.f, 0.f};

    #pragma unroll
    for (int ks = 0; ks < 4; ks++)
        #pragma unroll
        for (int nt = 0; nt < 8; nt++)
            acc2[nt] = __builtin_amdgcn_mfma_f32_16x16x32_bf16(
                a2[ks], u2_pack[(nt * 4 + ks) * 64 + lane], acc2[nt], 0, 0, 0);

    #pragma unroll
    for (int nt = 0; nt < 8; nt++) {
        int d = nt * 16 + l15;
        float c2v = c2[d];
        #pragma unroll
        for (int r = 0; r < 4; r++) {
            size_t idx = (size_t)(nbase + quad * 4 + r) * DD + d;
            out[idx] = hf[idx] + acc2[nt][r] + c2v;
        }
    }
}

extern "C" void kernel_launch(void* const* d_in, const int* in_sizes, int n_in,
                              void* d_out, int out_size, void* d_ws, size_t ws_size,
                              hipStream_t stream) {
    const float* h      = (const float*)d_in[0];
    const float* coords = (const float*)d_in[1];
    const int* ei       = (const int*)d_in[2];   // int64 in reference -> int32 from harness
    const float* W1 = (const float*)d_in[3];
    const float* b1 = (const float*)d_in[4];
    const float* W2 = (const float*)d_in[5];
    const float* b2 = (const float*)d_in[6];
    const float* U1 = (const float*)d_in[7];
    const float* c1 = (const float*)d_in[8];
    const float* U2 = (const float*)d_in[9];
    const float* c2 = (const float*)d_in[10];
    float* out = (float*)d_out;

    char* ws = (char*)d_ws;
    unsigned short* hp    = (unsigned short*)(ws);               // 12,800,000 B
    unsigned short* packs = (unsigned short*)(ws + 12800000);    //    196,608 B
    float* w1c            = (float*)(ws + 13000192);             //        512 B
    int* cnt              = (int*)(ws + 13001216);               //    200,000 B
    int* off              = (int*)(ws + 13201408);               //    200,004 B
    int* cursor           = (int*)(ws + 13401600);               //    200,000 B
    int* csr_send         = (int*)(ws + 13601792);               //  3,200,000 B
    unsigned short* G     = (unsigned short*)(ws + 16802048);    // 25,600,000 B
    const bf16x8* w1a = (const bf16x8*)(packs);
    const bf16x8* w1b = (const bf16x8*)(packs + 16384);
    const bf16x8* w2p = (const bf16x8*)(packs + 32768);
    const bf16x8* u1a = (const bf16x8*)(packs + 49152);
    const bf16x8* u1b = (const bf16x8*)(packs + 65536);
    const bf16x8* u2p = (const bf16x8*)(packs + 81920);

    prep_kernel<<<6250, 256, 0, stream>>>(h, hp, cnt);
    pack_w_kernel<<<3510, 256, 0, stream>>>(W1, W2, U1, U2, ei, packs, w1c, cnt);
    scan_kernel<<<1, 1024, 0, stream>>>(cnt, off, cursor);
    scatter_kernel<<<EE / 256, 256, 0, stream>>>(ei, cursor, csr_send);
    prep_g_kernel<<<(NN + 63) / 64, 256, 0, stream>>>(hp, w1a, w1b, b1, G);
    fused_kernel<<<(NN + 63) / 64, 256, 0, stream>>>(G, coords, csr_send, off,
                                                     w2p, w1c, b2, hp, h,
                                                     u1a, u1b, u2p, c1, c2, out);
}

// Round 4
// 524.186 us; speedup vs baseline: 2.2428x; 2.2428x over previous
//
#include <hip/hip_runtime.h>
#include <hip/hip_bf16.h>

#define NN 50000
#define EE 800000
#define DD 128

typedef __attribute__((ext_vector_type(8))) short bf16x8;
typedef __attribute__((ext_vector_type(4))) float f32x4;

__device__ __forceinline__ short f2bf(float f) {
    __hip_bfloat16 h = __float2bfloat16(f);
    return __builtin_bit_cast(short, h);
}

__device__ __forceinline__ float bf2f(short s) {
    unsigned int u = ((unsigned int)(unsigned short)s) << 16;
    return __builtin_bit_cast(float, u);
}

__device__ __forceinline__ float fast_silu(float x) {
    return x / (1.0f + __expf(-x));
}

// ---- prep_all: blocks [0,6250): h->bf16, zero agg, receiver histogram.
//      blocks [6250,6635): pack 6 weight blocks into MFMA B-frag order + w1c. ----
__global__ void prep_all_kernel(const float* __restrict__ h, unsigned short* __restrict__ hp,
                                float4* __restrict__ agg4, const int* __restrict__ ei,
                                int* __restrict__ cnt,
                                const float* __restrict__ W1, const float* __restrict__ W2,
                                const float* __restrict__ U1, const float* __restrict__ U2,
                                unsigned short* __restrict__ packs,
                                float* __restrict__ w1c_out) {
    if (blockIdx.x < 6250) {
        int t = blockIdx.x * blockDim.x + threadIdx.x;   // 1.6M threads exactly
        float4 v = ((const float4*)h)[t];
        ushort4 o;
        o.x = (unsigned short)f2bf(v.x);
        o.y = (unsigned short)f2bf(v.y);
        o.z = (unsigned short)f2bf(v.z);
        o.w = (unsigned short)f2bf(v.w);
        ((ushort4*)hp)[t] = o;
        agg4[t] = make_float4(0.f, 0.f, 0.f, 0.f);       // 6.4M floats exactly
        if (t < EE) atomicAdd(&cnt[ei[EE + t]], 1);      // receiver histogram
        return;
    }
    int t = (blockIdx.x - 6250) * blockDim.x + threadIdx.x;
    if (t >= 98304) {
        if (t < 98432) { int d = t - 98304; w1c_out[d] = W1[d * 257 + 256]; }
        return;
    }
    int mat = t >> 14;
    int r = t & 16383;
    int j = r & 7;
    int lane = (r >> 3) & 63;
    int f = r >> 9;            // 0..31
    int ks = f & 3, nt = f >> 2;
    int n = nt * 16 + (lane & 15);
    int k = ks * 32 + (lane >> 4) * 8 + j;
    float v;
    switch (mat) {
        case 0: v = W1[n * 257 + k];        break;  // W1a (vs h_sender)
        case 1: v = W1[n * 257 + 128 + k];  break;  // W1b (vs h_receiver)
        case 2: v = W2[n * 128 + k];        break;  // W2
        case 3: v = U1[n * 256 + k];        break;  // U1a (vs h)
        case 4: v = U1[n * 256 + 128 + k];  break;  // U1b (vs agg)
        default: v = U2[n * 128 + k];       break;  // U2
    }
    packs[t] = (unsigned short)f2bf(v);
}

// ---- scan: stripe-ownership exclusive scan (fully coalesced; bucket order is
//      arbitrary for CSR correctness — thread t owns receivers {t, t+1024, ...}) ----
__global__ void scan_kernel(const int* __restrict__ cnt, int* __restrict__ cursor) {
    __shared__ int part[1024];
    const int t = threadIdx.x;
    int s = 0;
    #pragma unroll
    for (int j = 0; j < 49; j++) {
        int i = j * 1024 + t;                        // coalesced
        if (i < NN) s += cnt[i];
    }
    part[t] = s;
    __syncthreads();
    for (int d = 1; d < 1024; d <<= 1) {
        int v = (t >= d) ? part[t - d] : 0;
        __syncthreads();
        part[t] += v;
        __syncthreads();
    }
    int base = (t == 0) ? 0 : part[t - 1];
    #pragma unroll
    for (int j = 0; j < 49; j++) {
        int i = j * 1024 + t;                        // coalesced
        if (i < NN) {
            cursor[i] = base;
            base += cnt[i];
        }
    }
}

// ---- prep_g (blocks [0,782)) + scatter (blocks [782,3907)) ----
__global__ __launch_bounds__(256, 2) void prep_g_scatter_kernel(
    const unsigned short* __restrict__ hp,
    const bf16x8* __restrict__ w1a_pack,
    const bf16x8* __restrict__ w1b_pack,
    const float* __restrict__ b1,
    unsigned short* __restrict__ G,
    const int* __restrict__ ei,
    int* __restrict__ cursor,
    int2* __restrict__ ssr)
{
    if (blockIdx.x >= 782) {
        // scatter edges into receiver-bucketed order
        int e = (blockIdx.x - 782) * 256 + threadIdx.x;   // 3125*256 = 800000 exactly
        int s = ei[e], r = ei[EE + e];
        int pos = atomicAdd(&cursor[r], 1);
        ssr[pos] = make_int2(s, r);
        return;
    }
    const int tid = threadIdx.x;
    const int wave = tid >> 6, lane = tid & 63;
    const int quad = lane >> 4, l15 = lane & 15;
    const int nbase = blockIdx.x * 64 + wave * 16;

    int n = nbase + l15;
    int nrow = n < NN ? n : NN - 1;

    bf16x8 ah[4];
    #pragma unroll
    for (int ks = 0; ks < 4; ks++)
        ah[ks] = *(const bf16x8*)(hp + (size_t)nrow * DD + ks * 32 + quad * 8);

    f32x4 acca[8], accb[8];
    #pragma unroll
    for (int nt = 0; nt < 8; nt++) {
        acca[nt] = f32x4{0.f, 0.f, 0.f, 0.f};
        accb[nt] = f32x4{0.f, 0.f, 0.f, 0.f};
    }

    #pragma unroll
    for (int ks = 0; ks < 4; ks++) {
        #pragma unroll
        for (int nt = 0; nt < 8; nt++)
            acca[nt] = __builtin_amdgcn_mfma_f32_16x16x32_bf16(
                ah[ks], w1a_pack[(nt * 4 + ks) * 64 + lane], acca[nt], 0, 0, 0);
        #pragma unroll
        for (int nt = 0; nt < 8; nt++)
            accb[nt] = __builtin_amdgcn_mfma_f32_16x16x32_bf16(
                ah[ks], w1b_pack[(nt * 4 + ks) * 64 + lane], accb[nt], 0, 0, 0);
    }

    #pragma unroll
    for (int nt = 0; nt < 8; nt++) {
        int d = nt * 16 + l15;
        float b1v = b1[d];
        #pragma unroll
        for (int r = 0; r < 4; r++) {
            int n2 = nbase + quad * 4 + r;
            if (n2 < NN) {
                G[(size_t)n2 * 256 + d]       = (unsigned short)f2bf(acca[nt][r] + b1v);
                G[(size_t)n2 * 256 + 128 + d] = (unsigned short)f2bf(accb[nt][r]);
            }
        }
    }
}

// ---- edge kernel v2 (receiver-sorted): gather G -> silu -> W2 MFMA ->
//      ballot-driven segmented reduce in registers; interior segments flushed
//      with PLAIN STORES, only wave-boundary segments use atomics. ----
__global__ __launch_bounds__(256, 3) void edge_kernel(
    const unsigned short* __restrict__ G,      // [NN][256] bf16: [G1a+b1 | G1b]
    const float* __restrict__ coords,          // [NN][3]
    const int2* __restrict__ ssr,              // [EE] (send, recv), receiver-bucketed
    const bf16x8* __restrict__ w2_pack,        // 32 KB
    const float* __restrict__ w1c,             // [128] fp32, k-order
    const float* __restrict__ b2,
    float* __restrict__ agg)                   // [NN][128] fp32, pre-zeroed
{
    __shared__ int send_s[4][64];
    __shared__ int recv_s[4][64];
    __shared__ float dist_s[4][64];

    const int tid = threadIdx.x;
    const int wave = tid >> 6, lane = tid & 63;
    const int quad = lane >> 4, l15 = lane & 15;
    const int ebase = blockIdx.x * 256 + wave * 64;

    {
        int2 sr = ssr[ebase + lane];
        send_s[wave][lane] = sr.x;
        recv_s[wave][lane] = sr.y;
        float dx = coords[3 * sr.x + 0] - coords[3 * sr.y + 0];
        float dy = coords[3 * sr.x + 1] - coords[3 * sr.y + 1];
        float dz = coords[3 * sr.x + 2] - coords[3 * sr.y + 2];
        dist_s[wave][lane] = sqrtf(dx * dx + dy * dy + dz * dz);
    }
    asm volatile("s_waitcnt lgkmcnt(0)" ::: "memory");   // wave-local LDS only

    // per-lane constants: w1c at k = ks*32 + quad*8 + j (this lane's A-frag k-range)
    float w1cf[4][8];
    #pragma unroll
    for (int ks = 0; ks < 4; ks++) {
        f32x4 c0 = *(const f32x4*)(w1c + ks * 32 + quad * 8);
        f32x4 c1 = *(const f32x4*)(w1c + ks * 32 + quad * 8 + 4);
        #pragma unroll
        for (int j = 0; j < 4; j++) { w1cf[ks][j] = c0[j]; w1cf[ks][4 + j] = c1[j]; }
    }
    float b2f[8];
    #pragma unroll
    for (int nt = 0; nt < 8; nt++) b2f[nt] = b2[nt * 16 + l15];

    // tile-0 gathers
    bf16x8 ga[4], gb[4];
    {
        int sr0 = send_s[wave][l15], rr0 = recv_s[wave][l15];
        #pragma unroll
        for (int ks = 0; ks < 4; ks++) {
            ga[ks] = *(const bf16x8*)(G + (size_t)sr0 * 256 + ks * 32 + quad * 8);
            gb[ks] = *(const bf16x8*)(G + (size_t)rr0 * 256 + 128 + ks * 32 + quad * 8);
        }
    }

    float carry[8];
    #pragma unroll
    for (int nt = 0; nt < 8; nt++) carry[nt] = 0.f;
    bool first_seg = true;     // first closed segment may extend into previous wave

    #pragma unroll
    for (int mt = 0; mt < 4; mt++) {
        const int rowg = mt * 16 + l15;
        const int myrecv = recv_s[wave][rowg];
        const int nxtrecv = (rowg < 63) ? recv_s[wave][rowg + 1] : myrecv;
        unsigned long long bal = __ballot(myrecv != nxtrecv);
        unsigned mask16 = (unsigned)(bal & 0xFFFFull);   // rows 0..15 (quads replicate)

        float dist = dist_s[wave][rowg];

        // layer-1 epilogue in A-frag layout
        bf16x8 m1f[4];
        #pragma unroll
        for (int ks = 0; ks < 4; ks++) {
            #pragma unroll
            for (int j = 0; j < 8; j++) {
                float pre = bf2f(ga[ks][j]) + bf2f(gb[ks][j]) + dist * w1cf[ks][j];
                m1f[ks][j] = f2bf(fast_silu(pre));
            }
        }

        // prefetch next tile's gathers early
        if (mt < 3) {
            int sr2 = send_s[wave][(mt + 1) * 16 + l15];
            int rr2 = recv_s[wave][(mt + 1) * 16 + l15];
            #pragma unroll
            for (int ks = 0; ks < 4; ks++) {
                ga[ks] = *(const bf16x8*)(G + (size_t)sr2 * 256 + ks * 32 + quad * 8);
                gb[ks] = *(const bf16x8*)(G + (size_t)rr2 * 256 + 128 + ks * 32 + quad * 8);
            }
        }

        // layer 2: W2 MFMA, then silu in place -> sv
        f32x4 sv[8];
        #pragma unroll
        for (int nt = 0; nt < 8; nt++) sv[nt] = f32x4{0.f, 0.f, 0.f, 0.f};
        #pragma unroll
        for (int ks = 0; ks < 4; ks++)
            #pragma unroll
            for (int nt = 0; nt < 8; nt++)
                sv[nt] = __builtin_amdgcn_mfma_f32_16x16x32_bf16(
                    m1f[ks], w2_pack[(nt * 4 + ks) * 64 + lane], sv[nt], 0, 0, 0);
        #pragma unroll
        for (int nt = 0; nt < 8; nt++)
            #pragma unroll
            for (int r = 0; r < 4; r++)
                sv[nt][r] = fast_silu(sv[nt][r] + b2f[nt]);

        // segmented reduce over the tile's 16 receiver-sorted rows (uniform control)
        int i0 = 0;
        unsigned m = mask16;
        while (m) {
            int b = (int)__builtin_ctz(m);   // segment rows [i0, b] close here
            m &= m - 1;
            float tot[8];
            #pragma unroll
            for (int nt = 0; nt < 8; nt++) {
                float s = 0.f;
                #pragma unroll
                for (int r = 0; r < 4; r++) {
                    int row = quad * 4 + r;
                    s += (row >= i0 && row <= b) ? sv[nt][r] : 0.f;
                }
                s += __shfl_xor(s, 16);
                s += __shfl_xor(s, 32);      // all lanes now hold col total
                tot[nt] = s;
            }
            if (i0 == 0) {                   // segment continues the carried one
                #pragma unroll
                for (int nt = 0; nt < 8; nt++) { tot[nt] += carry[nt]; carry[nt] = 0.f; }
            }
            int rcv = __shfl(myrecv, i0);    // uniform receiver id
            size_t base = (size_t)rcv * DD + l15;
            float v0 = tot[quad * 2 + 0], v1 = tot[quad * 2 + 1];
            if (first_seg) {                 // may extend into previous wave
                unsafeAtomicAdd(&agg[base + (quad * 2 + 0) * 16], v0);
                unsafeAtomicAdd(&agg[base + (quad * 2 + 1) * 16], v1);
                first_seg = false;
            } else {                         // interior: exclusively ours
                agg[base + (quad * 2 + 0) * 16] = v0;
                agg[base + (quad * 2 + 1) * 16] = v1;
            }
            i0 = b + 1;
        }
        if (i0 <= 15) {                      // trailing rows -> carry
            #pragma unroll
            for (int nt = 0; nt < 8; nt++) {
                float s = 0.f;
                #pragma unroll
                for (int r = 0; r < 4; r++) {
                    int row = quad * 4 + r;
                    s += (row >= i0) ? sv[nt][r] : 0.f;
                }
                s += __shfl_xor(s, 16);
                s += __shfl_xor(s, 32);
                carry[nt] += s;
            }
        }
    }
    // final carry flush (may extend into next wave): atomic
    {
        int rcv = recv_s[wave][63];
        size_t base = (size_t)rcv * DD + l15;
        unsafeAtomicAdd(&agg[base + (quad * 2 + 0) * 16], carry[quad * 2 + 0]);
        unsafeAtomicAdd(&agg[base + (quad * 2 + 1) * 16], carry[quad * 2 + 1]);
    }
}

// ---- node kernel: out = h + U2*silu(U1a*h + U1b*agg + c1) + c2 ----
__global__ __launch_bounds__(256, 4) void node_kernel(
    const unsigned short* __restrict__ hp,
    const float* __restrict__ hf,
    const float* __restrict__ agg,
    const bf16x8* __restrict__ u1a_pack,
    const bf16x8* __restrict__ u1b_pack,
    const bf16x8* __restrict__ u2_pack,
    const float* __restrict__ c1,
    const float* __restrict__ c2,
    float* __restrict__ out)
{
    __shared__ unsigned short u1s[4][16][136];

    const int tid = threadIdx.x;
    const int wave = tid >> 6, lane = tid & 63;
    const int quad = lane >> 4, l15 = lane & 15;
    const int nbase = blockIdx.x * 64 + wave * 16;

    int n = nbase + l15;
    int nrow = n < NN ? n : NN - 1;

    float c1v[8];
    #pragma unroll
    for (int nt = 0; nt < 8; nt++) c1v[nt] = c1[nt * 16 + l15];

    bf16x8 ah[4], ag[4];
    #pragma unroll
    for (int ks = 0; ks < 4; ks++) {
        ah[ks] = *(const bf16x8*)(hp + (size_t)nrow * DD + ks * 32 + quad * 8);
        const float* ap = agg + (size_t)nrow * DD + ks * 32 + quad * 8;
        f32x4 g0 = *(const f32x4*)ap;
        f32x4 g1 = *(const f32x4*)(ap + 4);
        bf16x8 t;
        t[0] = f2bf(g0[0]); t[1] = f2bf(g0[1]); t[2] = f2bf(g0[2]); t[3] = f2bf(g0[3]);
        t[4] = f2bf(g1[0]); t[5] = f2bf(g1[1]); t[6] = f2bf(g1[2]); t[7] = f2bf(g1[3]);
        ag[ks] = t;
    }

    f32x4 acc[8];
    #pragma unroll
    for (int nt = 0; nt < 8; nt++) acc[nt] = f32x4{0.f, 0.f, 0.f, 0.f};

    #pragma unroll
    for (int ks = 0; ks < 4; ks++) {
        #pragma unroll
        for (int nt = 0; nt < 8; nt++)
            acc[nt] = __builtin_amdgcn_mfma_f32_16x16x32_bf16(
                ah[ks], u1a_pack[(nt * 4 + ks) * 64 + lane], acc[nt], 0, 0, 0);
        #pragma unroll
        for (int nt = 0; nt < 8; nt++)
            acc[nt] = __builtin_amdgcn_mfma_f32_16x16x32_bf16(
                ag[ks], u1b_pack[(nt * 4 + ks) * 64 + lane], acc[nt], 0, 0, 0);
    }

    #pragma unroll
    for (int nt = 0; nt < 8; nt++) {
        int d = nt * 16 + l15;
        #pragma unroll
        for (int r = 0; r < 4; r++) {
            float pre = acc[nt][r] + c1v[nt];
            u1s[wave][quad * 4 + r][d] = (unsigned short)f2bf(fast_silu(pre));
        }
    }
    asm volatile("s_waitcnt lgkmcnt(0)" ::: "memory");

    bf16x8 a2[4];
    #pragma unroll
    for (int ks = 0; ks < 4; ks++)
        a2[ks] = *(const bf16x8*)(&u1s[wave][l15][ks * 32 + quad * 8]);

    f32x4 acc2[8];
    #pragma unroll
    for (int nt = 0; nt < 8; nt++) acc2[nt] = f32x4{0.f, 0.f, 0.f, 0.f};

    #pragma unroll
    for (int ks = 0; ks < 4; ks++)
        #pragma unroll
        for (int nt = 0; nt < 8; nt++)
            acc2[nt] = __builtin_amdgcn_mfma_f32_16x16x32_bf16(
                a2[ks], u2_pack[(nt * 4 + ks) * 64 + lane], acc2[nt], 0, 0, 0);

    #pragma unroll
    for (int nt = 0; nt < 8; nt++) {
        int d = nt * 16 + l15;
        float c2v = c2[d];
        #pragma unroll
        for (int r = 0; r < 4; r++) {
            int n2 = nbase + quad * 4 + r;
            if (n2 < NN) {
                size_t idx = (size_t)n2 * DD + d;
                out[idx] = hf[idx] + acc2[nt][r] + c2v;
            }
        }
    }
}

extern "C" void kernel_launch(void* const* d_in, const int* in_sizes, int n_in,
                              void* d_out, int out_size, void* d_ws, size_t ws_size,
                              hipStream_t stream) {
    const float* h      = (const float*)d_in[0];
    const float* coords = (const float*)d_in[1];
    const int* ei       = (const int*)d_in[2];   // int64 in reference -> int32 from harness
    const float* W1 = (const float*)d_in[3];
    const float* b1 = (const float*)d_in[4];
    const float* W2 = (const float*)d_in[5];
    const float* b2 = (const float*)d_in[6];
    const float* U1 = (const float*)d_in[7];
    const float* c1 = (const float*)d_in[8];
    const float* U2 = (const float*)d_in[9];
    const float* c2 = (const float*)d_in[10];
    float* out = (float*)d_out;

    char* ws = (char*)d_ws;
    float* agg            = (float*)ws;                          // 25,600,000 B fp32 [NN][128]
    unsigned short* hp    = (unsigned short*)(ws + 25600000);    // 12,800,000 B bf16 h
    unsigned short* packs = (unsigned short*)(ws + 38400000);    //    196,608 B packed weights
    float* w1c            = (float*)(ws + 38600000);             //        512 B
    unsigned short* G     = (unsigned short*)(ws + 38700000);    // 25,600,000 B bf16 [NN][256]
    int* cnt              = (int*)(ws + 64300000);               //    200,000 B
    int* cursor           = (int*)(ws + 64500000);               //    200,000 B
    int2* ssr             = (int2*)(ws + 64700000);              //  6,400,000 B sorted (s,r)
    const bf16x8* w1a = (const bf16x8*)(packs);
    const bf16x8* w1b = (const bf16x8*)(packs + 16384);
    const bf16x8* w2p = (const bf16x8*)(packs + 32768);
    const bf16x8* u1a = (const bf16x8*)(packs + 49152);
    const bf16x8* u1b = (const bf16x8*)(packs + 65536);
    const bf16x8* u2p = (const bf16x8*)(packs + 81920);

    hipMemsetAsync(cnt, 0, NN * sizeof(int), stream);
    prep_all_kernel<<<6635, 256, 0, stream>>>(h, hp, (float4*)agg, ei, cnt,
                                              W1, W2, U1, U2, packs, w1c);
    scan_kernel<<<1, 1024, 0, stream>>>(cnt, cursor);
    prep_g_scatter_kernel<<<3907, 256, 0, stream>>>(hp, w1a, w1b, b1, G, ei, cursor, ssr);
    edge_kernel<<<EE / 256, 256, 0, stream>>>(G, coords, ssr, w2p, w1c, b2, agg);
    node_kernel<<<(NN + 63) / 64, 256, 0, stream>>>(hp, h, agg, u1a, u1b, u2p, c1, c2, out);
}

// Round 5
// 519.547 us; speedup vs baseline: 2.2628x; 1.0089x over previous
//
#include <hip/hip_runtime.h>
#include <hip/hip_bf16.h>

#define NN 50000
#define EE 800000
#define DD 128

typedef __attribute__((ext_vector_type(8))) short bf16x8;
typedef __attribute__((ext_vector_type(4))) float f32x4;

__device__ __forceinline__ short f2bf(float f) {
    __hip_bfloat16 h = __float2bfloat16(f);
    return __builtin_bit_cast(short, h);
}

__device__ __forceinline__ float bf2f(short s) {
    unsigned int u = ((unsigned int)(unsigned short)s) << 16;
    return __builtin_bit_cast(float, u);
}

__device__ __forceinline__ float fast_silu(float x) {
    return x / (1.0f + __expf(-x));
}

// ---- prep_all: blocks [0,6250): h->bf16, zero agg, receiver histogram.
//      blocks [6250,6635): pack 6 weight blocks into MFMA B-frag order + w1c. ----
__global__ void prep_all_kernel(const float* __restrict__ h, unsigned short* __restrict__ hp,
                                float4* __restrict__ agg4, const int* __restrict__ ei,
                                int* __restrict__ cnt,
                                const float* __restrict__ W1, const float* __restrict__ W2,
                                const float* __restrict__ U1, const float* __restrict__ U2,
                                unsigned short* __restrict__ packs,
                                float* __restrict__ w1c_out) {
    if (blockIdx.x < 6250) {
        int t = blockIdx.x * blockDim.x + threadIdx.x;   // 1.6M threads exactly
        float4 v = ((const float4*)h)[t];
        ushort4 o;
        o.x = (unsigned short)f2bf(v.x);
        o.y = (unsigned short)f2bf(v.y);
        o.z = (unsigned short)f2bf(v.z);
        o.w = (unsigned short)f2bf(v.w);
        ((ushort4*)hp)[t] = o;
        agg4[t] = make_float4(0.f, 0.f, 0.f, 0.f);       // 6.4M floats exactly
        if (t < EE) atomicAdd(&cnt[ei[EE + t]], 1);      // receiver histogram
        return;
    }
    int t = (blockIdx.x - 6250) * blockDim.x + threadIdx.x;
    if (t >= 98304) {
        if (t < 98432) { int d = t - 98304; w1c_out[d] = W1[d * 257 + 256]; }
        return;
    }
    int mat = t >> 14;
    int r = t & 16383;
    int j = r & 7;
    int lane = (r >> 3) & 63;
    int f = r >> 9;            // 0..31
    int ks = f & 3, nt = f >> 2;
    int n = nt * 16 + (lane & 15);
    int k = ks * 32 + (lane >> 4) * 8 + j;
    float v;
    switch (mat) {
        case 0: v = W1[n * 257 + k];        break;  // W1a (vs h_sender)
        case 1: v = W1[n * 257 + 128 + k];  break;  // W1b (vs h_receiver)
        case 2: v = W2[n * 128 + k];        break;  // W2
        case 3: v = U1[n * 256 + k];        break;  // U1a (vs h)
        case 4: v = U1[n * 256 + 128 + k];  break;  // U1b (vs agg)
        default: v = U2[n * 128 + k];       break;  // U2
    }
    packs[t] = (unsigned short)f2bf(v);
}

// ---- scan: stripe-ownership exclusive scan (fully coalesced; bucket order is
//      arbitrary for CSR correctness — thread t owns receivers {t, t+1024, ...}) ----
__global__ void scan_kernel(const int* __restrict__ cnt, int* __restrict__ cursor) {
    __shared__ int part[1024];
    const int t = threadIdx.x;
    int s = 0;
    #pragma unroll
    for (int j = 0; j < 49; j++) {
        int i = j * 1024 + t;                        // coalesced
        if (i < NN) s += cnt[i];
    }
    part[t] = s;
    __syncthreads();
    for (int d = 1; d < 1024; d <<= 1) {
        int v = (t >= d) ? part[t - d] : 0;
        __syncthreads();
        part[t] += v;
        __syncthreads();
    }
    int base = (t == 0) ? 0 : part[t - 1];
    #pragma unroll
    for (int j = 0; j < 49; j++) {
        int i = j * 1024 + t;                        // coalesced
        if (i < NN) {
            cursor[i] = base;
            base += cnt[i];
        }
    }
}

// ---- prep_g (blocks [0,782)) + scatter (blocks [782,3907)) ----
__global__ __launch_bounds__(256, 2) void prep_g_scatter_kernel(
    const unsigned short* __restrict__ hp,
    const bf16x8* __restrict__ w1a_pack,
    const bf16x8* __restrict__ w1b_pack,
    const float* __restrict__ b1,
    unsigned short* __restrict__ G,
    const int* __restrict__ ei,
    int* __restrict__ cursor,
    int2* __restrict__ ssr)
{
    if (blockIdx.x >= 782) {
        // scatter edges into receiver-bucketed order
        int e = (blockIdx.x - 782) * 256 + threadIdx.x;   // 3125*256 = 800000 exactly
        int s = ei[e], r = ei[EE + e];
        int pos = atomicAdd(&cursor[r], 1);
        ssr[pos] = make_int2(s, r);
        return;
    }
    const int tid = threadIdx.x;
    const int wave = tid >> 6, lane = tid & 63;
    const int quad = lane >> 4, l15 = lane & 15;
    const int nbase = blockIdx.x * 64 + wave * 16;

    int n = nbase + l15;
    int nrow = n < NN ? n : NN - 1;

    bf16x8 ah[4];
    #pragma unroll
    for (int ks = 0; ks < 4; ks++)
        ah[ks] = *(const bf16x8*)(hp + (size_t)nrow * DD + ks * 32 + quad * 8);

    f32x4 acca[8], accb[8];
    #pragma unroll
    for (int nt = 0; nt < 8; nt++) {
        acca[nt] = f32x4{0.f, 0.f, 0.f, 0.f};
        accb[nt] = f32x4{0.f, 0.f, 0.f, 0.f};
    }

    #pragma unroll
    for (int ks = 0; ks < 4; ks++) {
        #pragma unroll
        for (int nt = 0; nt < 8; nt++)
            acca[nt] = __builtin_amdgcn_mfma_f32_16x16x32_bf16(
                ah[ks], w1a_pack[(nt * 4 + ks) * 64 + lane], acca[nt], 0, 0, 0);
        #pragma unroll
        for (int nt = 0; nt < 8; nt++)
            accb[nt] = __builtin_amdgcn_mfma_f32_16x16x32_bf16(
                ah[ks], w1b_pack[(nt * 4 + ks) * 64 + lane], accb[nt], 0, 0, 0);
    }

    #pragma unroll
    for (int nt = 0; nt < 8; nt++) {
        int d = nt * 16 + l15;
        float b1v = b1[d];
        #pragma unroll
        for (int r = 0; r < 4; r++) {
            int n2 = nbase + quad * 4 + r;
            if (n2 < NN) {
                G[(size_t)n2 * 256 + d]       = (unsigned short)f2bf(acca[nt][r] + b1v);
                G[(size_t)n2 * 256 + 128 + d] = (unsigned short)f2bf(accb[nt][r]);
            }
        }
    }
}

// ---- edge kernel v3 (receiver-sorted): gather G -> silu -> W2 MFMA ->
//      ballot-driven segmented reduce; interior segments flushed with PLAIN
//      STORES, only wave-boundary segments use atomics.
//      v3: w1c in per-wave LDS (-32 VGPR), launch_bounds 4, XCD block swizzle. ----
__global__ __launch_bounds__(256, 4) void edge_kernel(
    const unsigned short* __restrict__ G,      // [NN][256] bf16: [G1a+b1 | G1b]
    const float* __restrict__ coords,          // [NN][3]
    const int2* __restrict__ ssr,              // [EE] (send, recv), receiver-bucketed
    const bf16x8* __restrict__ w2_pack,        // 32 KB
    const float* __restrict__ w1c,             // [128] fp32, k-order
    const float* __restrict__ b2,
    float* __restrict__ agg)                   // [NN][128] fp32, pre-zeroed
{
    __shared__ int send_s[4][64];
    __shared__ int recv_s[4][64];
    __shared__ float dist_s[4][64];
    __shared__ float w1c_s[4][128];            // per-wave copy (no block sync needed)

    const int tid = threadIdx.x;
    const int wave = tid >> 6, lane = tid & 63;
    const int quad = lane >> 4, l15 = lane & 15;

    // bijective XCD-aware swizzle: consecutive logical blocks (which stream a
    // contiguous receiver window and share boundary rows) colocate on one XCD.
    const int nwg = 3125, q = nwg >> 3, r8 = nwg & 7;   // q=390, r8=5
    int xcd = (int)blockIdx.x & 7, idx = (int)blockIdx.x >> 3;
    int bid = (xcd < r8) ? xcd * (q + 1) + idx
                         : r8 * (q + 1) + (xcd - r8) * q + idx;
    const int ebase = bid * 256 + wave * 64;

    {
        int2 sr = ssr[ebase + lane];
        send_s[wave][lane] = sr.x;
        recv_s[wave][lane] = sr.y;
        float dx = coords[3 * sr.x + 0] - coords[3 * sr.y + 0];
        float dy = coords[3 * sr.x + 1] - coords[3 * sr.y + 1];
        float dz = coords[3 * sr.x + 2] - coords[3 * sr.y + 2];
        dist_s[wave][lane] = sqrtf(dx * dx + dy * dy + dz * dz);
        w1c_s[wave][lane] = w1c[lane];
        w1c_s[wave][64 + lane] = w1c[64 + lane];
    }
    asm volatile("s_waitcnt lgkmcnt(0)" ::: "memory");   // wave-local LDS only

    float b2f[8];
    #pragma unroll
    for (int nt = 0; nt < 8; nt++) b2f[nt] = b2[nt * 16 + l15];

    // tile-0 gathers
    bf16x8 ga[4], gb[4];
    {
        int sr0 = send_s[wave][l15], rr0 = recv_s[wave][l15];
        #pragma unroll
        for (int ks = 0; ks < 4; ks++) {
            ga[ks] = *(const bf16x8*)(G + (size_t)sr0 * 256 + ks * 32 + quad * 8);
            gb[ks] = *(const bf16x8*)(G + (size_t)rr0 * 256 + 128 + ks * 32 + quad * 8);
        }
    }

    float carry[8];
    #pragma unroll
    for (int nt = 0; nt < 8; nt++) carry[nt] = 0.f;
    bool first_seg = true;     // first closed segment may extend into previous wave

    #pragma unroll
    for (int mt = 0; mt < 4; mt++) {
        const int rowg = mt * 16 + l15;
        const int myrecv = recv_s[wave][rowg];
        const int nxtrecv = (rowg < 63) ? recv_s[wave][rowg + 1] : myrecv;
        unsigned long long bal = __ballot(myrecv != nxtrecv);
        unsigned mask16 = (unsigned)(bal & 0xFFFFull);   // rows 0..15 (quads replicate)

        float dist = dist_s[wave][rowg];

        // layer-1 epilogue in A-frag layout (w1c read from LDS, quad-broadcast)
        bf16x8 m1f[4];
        #pragma unroll
        for (int ks = 0; ks < 4; ks++) {
            f32x4 c0 = *(const f32x4*)&w1c_s[wave][ks * 32 + quad * 8];
            f32x4 c1 = *(const f32x4*)&w1c_s[wave][ks * 32 + quad * 8 + 4];
            #pragma unroll
            for (int j = 0; j < 4; j++) {
                float pre0 = bf2f(ga[ks][j])     + bf2f(gb[ks][j])     + dist * c0[j];
                float pre1 = bf2f(ga[ks][4 + j]) + bf2f(gb[ks][4 + j]) + dist * c1[j];
                m1f[ks][j]     = f2bf(fast_silu(pre0));
                m1f[ks][4 + j] = f2bf(fast_silu(pre1));
            }
        }

        // prefetch next tile's gathers early
        if (mt < 3) {
            int sr2 = send_s[wave][(mt + 1) * 16 + l15];
            int rr2 = recv_s[wave][(mt + 1) * 16 + l15];
            #pragma unroll
            for (int ks = 0; ks < 4; ks++) {
                ga[ks] = *(const bf16x8*)(G + (size_t)sr2 * 256 + ks * 32 + quad * 8);
                gb[ks] = *(const bf16x8*)(G + (size_t)rr2 * 256 + 128 + ks * 32 + quad * 8);
            }
        }

        // layer 2: W2 MFMA, then silu in place -> sv
        f32x4 sv[8];
        #pragma unroll
        for (int nt = 0; nt < 8; nt++) sv[nt] = f32x4{0.f, 0.f, 0.f, 0.f};
        #pragma unroll
        for (int ks = 0; ks < 4; ks++)
            #pragma unroll
            for (int nt = 0; nt < 8; nt++)
                sv[nt] = __builtin_amdgcn_mfma_f32_16x16x32_bf16(
                    m1f[ks], w2_pack[(nt * 4 + ks) * 64 + lane], sv[nt], 0, 0, 0);
        #pragma unroll
        for (int nt = 0; nt < 8; nt++)
            #pragma unroll
            for (int r = 0; r < 4; r++)
                sv[nt][r] = fast_silu(sv[nt][r] + b2f[nt]);

        // segmented reduce over the tile's 16 receiver-sorted rows (uniform control)
        int i0 = 0;
        unsigned m = mask16;
        while (m) {
            int b = (int)__builtin_ctz(m);   // segment rows [i0, b] close here
            m &= m - 1;
            float tot[8];
            #pragma unroll
            for (int nt = 0; nt < 8; nt++) {
                float s = 0.f;
                #pragma unroll
                for (int r = 0; r < 4; r++) {
                    int row = quad * 4 + r;
                    s += (row >= i0 && row <= b) ? sv[nt][r] : 0.f;
                }
                s += __shfl_xor(s, 16);
                s += __shfl_xor(s, 32);      // all lanes now hold col total
                tot[nt] = s;
            }
            if (i0 == 0) {                   // segment continues the carried one
                #pragma unroll
                for (int nt = 0; nt < 8; nt++) { tot[nt] += carry[nt]; carry[nt] = 0.f; }
            }
            int rcv = __shfl(myrecv, i0);    // uniform receiver id
            size_t base = (size_t)rcv * DD + l15;
            float v0 = tot[quad * 2 + 0], v1 = tot[quad * 2 + 1];
            if (first_seg) {                 // may extend into previous wave
                unsafeAtomicAdd(&agg[base + (quad * 2 + 0) * 16], v0);
                unsafeAtomicAdd(&agg[base + (quad * 2 + 1) * 16], v1);
                first_seg = false;
            } else {                         // interior: exclusively ours
                agg[base + (quad * 2 + 0) * 16] = v0;
                agg[base + (quad * 2 + 1) * 16] = v1;
            }
            i0 = b + 1;
        }
        if (i0 <= 15) {                      // trailing rows -> carry
            #pragma unroll
            for (int nt = 0; nt < 8; nt++) {
                float s = 0.f;
                #pragma unroll
                for (int r = 0; r < 4; r++) {
                    int row = quad * 4 + r;
                    s += (row >= i0) ? sv[nt][r] : 0.f;
                }
                s += __shfl_xor(s, 16);
                s += __shfl_xor(s, 32);
                carry[nt] += s;
            }
        }
    }
    // final carry flush (may extend into next wave): atomic
    {
        int rcv = recv_s[wave][63];
        size_t base = (size_t)rcv * DD + l15;
        unsafeAtomicAdd(&agg[base + (quad * 2 + 0) * 16], carry[quad * 2 + 0]);
        unsafeAtomicAdd(&agg[base + (quad * 2 + 1) * 16], carry[quad * 2 + 1]);
    }
}

// ---- node kernel: out = h + U2*silu(U1a*h + U1b*agg + c1) + c2 ----
__global__ __launch_bounds__(256, 4) void node_kernel(
    const unsigned short* __restrict__ hp,
    const float* __restrict__ hf,
    const float* __restrict__ agg,
    const bf16x8* __restrict__ u1a_pack,
    const bf16x8* __restrict__ u1b_pack,
    const bf16x8* __restrict__ u2_pack,
    const float* __restrict__ c1,
    const float* __restrict__ c2,
    float* __restrict__ out)
{
    __shared__ unsigned short u1s[4][16][136];

    const int tid = threadIdx.x;
    const int wave = tid >> 6, lane = tid & 63;
    const int quad = lane >> 4, l15 = lane & 15;
    const int nbase = blockIdx.x * 64 + wave * 16;

    int n = nbase + l15;
    int nrow = n < NN ? n : NN - 1;

    float c1v[8];
    #pragma unroll
    for (int nt = 0; nt < 8; nt++) c1v[nt] = c1[nt * 16 + l15];

    bf16x8 ah[4], ag[4];
    #pragma unroll
    for (int ks = 0; ks < 4; ks++) {
        ah[ks] = *(const bf16x8*)(hp + (size_t)nrow * DD + ks * 32 + quad * 8);
        const float* ap = agg + (size_t)nrow * DD + ks * 32 + quad * 8;
        f32x4 g0 = *(const f32x4*)ap;
        f32x4 g1 = *(const f32x4*)(ap + 4);
        bf16x8 t;
        t[0] = f2bf(g0[0]); t[1] = f2bf(g0[1]); t[2] = f2bf(g0[2]); t[3] = f2bf(g0[3]);
        t[4] = f2bf(g1[0]); t[5] = f2bf(g1[1]); t[6] = f2bf(g1[2]); t[7] = f2bf(g1[3]);
        ag[ks] = t;
    }

    f32x4 acc[8];
    #pragma unroll
    for (int nt = 0; nt < 8; nt++) acc[nt] = f32x4{0.f, 0.f, 0.f, 0.f};

    #pragma unroll
    for (int ks = 0; ks < 4; ks++) {
        #pragma unroll
        for (int nt = 0; nt < 8; nt++)
            acc[nt] = __builtin_amdgcn_mfma_f32_16x16x32_bf16(
                ah[ks], u1a_pack[(nt * 4 + ks) * 64 + lane], acc[nt], 0, 0, 0);
        #pragma unroll
        for (int nt = 0; nt < 8; nt++)
            acc[nt] = __builtin_amdgcn_mfma_f32_16x16x32_bf16(
                ag[ks], u1b_pack[(nt * 4 + ks) * 64 + lane], acc[nt], 0, 0, 0);
    }

    #pragma unroll
    for (int nt = 0; nt < 8; nt++) {
        int d = nt * 16 + l15;
        #pragma unroll
        for (int r = 0; r < 4; r++) {
            float pre = acc[nt][r] + c1v[nt];
            u1s[wave][quad * 4 + r][d] = (unsigned short)f2bf(fast_silu(pre));
        }
    }
    asm volatile("s_waitcnt lgkmcnt(0)" ::: "memory");

    bf16x8 a2[4];
    #pragma unroll
    for (int ks = 0; ks < 4; ks++)
        a2[ks] = *(const bf16x8*)(&u1s[wave][l15][ks * 32 + quad * 8]);

    f32x4 acc2[8];
    #pragma unroll
    for (int nt = 0; nt < 8; nt++) acc2[nt] = f32x4{0.f, 0.f, 0.f, 0.f};

    #pragma unroll
    for (int ks = 0; ks < 4; ks++)
        #pragma unroll
        for (int nt = 0; nt < 8; nt++)
            acc2[nt] = __builtin_amdgcn_mfma_f32_16x16x32_bf16(
                a2[ks], u2_pack[(nt * 4 + ks) * 64 + lane], acc2[nt], 0, 0, 0);

    #pragma unroll
    for (int nt = 0; nt < 8; nt++) {
        int d = nt * 16 + l15;
        float c2v = c2[d];
        #pragma unroll
        for (int r = 0; r < 4; r++) {
            int n2 = nbase + quad * 4 + r;
            if (n2 < NN) {
                size_t idx = (size_t)n2 * DD + d;
                out[idx] = hf[idx] + acc2[nt][r] + c2v;
            }
        }
    }
}

extern "C" void kernel_launch(void* const* d_in, const int* in_sizes, int n_in,
                              void* d_out, int out_size, void* d_ws, size_t ws_size,
                              hipStream_t stream) {
    const float* h      = (const float*)d_in[0];
    const float* coords = (const float*)d_in[1];
    const int* ei       = (const int*)d_in[2];   // int64 in reference -> int32 from harness
    const float* W1 = (const float*)d_in[3];
    const float* b1 = (const float*)d_in[4];
    const float* W2 = (const float*)d_in[5];
    const float* b2 = (const float*)d_in[6];
    const float* U1 = (const float*)d_in[7];
    const float* c1 = (const float*)d_in[8];
    const float* U2 = (const float*)d_in[9];
    const float* c2 = (const float*)d_in[10];
    float* out = (float*)d_out;

    char* ws = (char*)d_ws;
    float* agg            = (float*)ws;                          // 25,600,000 B fp32 [NN][128]
    unsigned short* hp    = (unsigned short*)(ws + 25600000);    // 12,800,000 B bf16 h
    unsigned short* packs = (unsigned short*)(ws + 38400000);    //    196,608 B packed weights
    float* w1c            = (float*)(ws + 38600000);             //        512 B
    unsigned short* G     = (unsigned short*)(ws + 38700000);    // 25,600,000 B bf16 [NN][256]
    int* cnt              = (int*)(ws + 64300000);               //    200,000 B
    int* cursor           = (int*)(ws + 64500000);               //    200,000 B
    int2* ssr             = (int2*)(ws + 64700000);              //  6,400,000 B sorted (s,r)
    const bf16x8* w1a = (const bf16x8*)(packs);
    const bf16x8* w1b = (const bf16x8*)(packs + 16384);
    const bf16x8* w2p = (const bf16x8*)(packs + 32768);
    const bf16x8* u1a = (const bf16x8*)(packs + 49152);
    const bf16x8* u1b = (const bf16x8*)(packs + 65536);
    const bf16x8* u2p = (const bf16x8*)(packs + 81920);

    hipMemsetAsync(cnt, 0, NN * sizeof(int), stream);
    prep_all_kernel<<<6635, 256, 0, stream>>>(h, hp, (float4*)agg, ei, cnt,
                                              W1, W2, U1, U2, packs, w1c);
    scan_kernel<<<1, 1024, 0, stream>>>(cnt, cursor);
    prep_g_scatter_kernel<<<3907, 256, 0, stream>>>(hp, w1a, w1b, b1, G, ei, cursor, ssr);
    edge_kernel<<<EE / 256, 256, 0, stream>>>(G, coords, ssr, w2p, w1c, b2, agg);
    node_kernel<<<(NN + 63) / 64, 256, 0, stream>>>(hp, h, agg, u1a, u1b, u2p, c1, c2, out);
}